// Round 10
// baseline (29926.727 us; speedup 1.0000x reference)
//
#include <hip/hip_runtime.h>

typedef _Float16 f16x8 __attribute__((ext_vector_type(8)));
typedef float    f32x4 __attribute__((ext_vector_type(4)));
typedef unsigned long long u64;
typedef u64 u64x2 __attribute__((ext_vector_type(2)));

constexpr int BATCH = 1024;
constexpr int HDIM  = 512;
constexpr int TENC  = 512;
constexpr int PRED  = 48;
constexpr int STEPS = TENC + PRED - 1;   // 559 cell steps; loop runs 560 (last = fc only)
constexpr int NGRP  = 32;
constexpr int GBAT  = 32;
constexpr int UBU   = 64;                // units per block (4 waves x 16)
constexpr int HB_OFF = 32768;
constexpr int LIMIT = 4096;              // poll rounds before self-heal republish

// In-band tag (R7/R8-proven): each 4B dword of stored h carries step tag at
// bit0/bit16. h_t in buffer t&1, tag t&3; 2-bit tag + ping-pong is ABA-safe
// (max skew 1 step).
constexpr u64 TAG_MASK = 0x0001000100010001ull;
__device__ __forceinline__ u64 tag_of(int t) {
  return ((u64)(t & 1) | ((u64)((t >> 1) & 1) << 16)) * 0x0000000100000001ull;
}

__global__ void init_kernel(int* wsi) {
  int idx = blockIdx.x * blockDim.x + threadIdx.x;
  int stride = gridDim.x * blockDim.x;
  const int nws = (HB_OFF + BATCH * HDIM * 2) / 4;  // hbuf[0] = h_0 = 0 (tag 00)
  for (int i = idx; i < nws; i += stride) wsi[i] = 0;
  // hbuf[1] stays 0xAA poison -> tag-invalid until written
}

// LLC-scope (cross-XCD safe):
static __device__ __forceinline__ f16x8 load16_llc(const _Float16* p) {
  f16x8 v;
  asm volatile("global_load_dwordx4 %0, %1, off sc0 sc1"
               : "=v"(v) : "v"((u64)p) : "memory");
  return v;
}
// L2-scope (same-XCD; bypass L1, hit the XCD's shared L2):
static __device__ __forceinline__ f16x8 load16_l2(const _Float16* p) {
  f16x8 v;
  asm volatile("global_load_dwordx4 %0, %1, off sc0"
               : "=v"(v) : "v"((u64)p) : "memory");
  return v;
}
static __device__ __forceinline__ void store8_l2(_Float16* p, u64 d) {
  asm volatile("global_store_dwordx2 %0, %1, off sc0"
               :: "v"((u64)p), "v"(d) : "memory");
}

// R8 dataflow + L2-scope exchange with self-healing scope demotion.
// Static grouping (bid&31): under round-robin dispatch a group's 8 blocks
// share one XCD, so sc0 stores/loads meet in that XCD's L2 (~200cyc RT vs
// ~600+ LLC). Correctness never depends on placement: if a poll loop
// exhausts LIMIT rounds, the block republishes its current AND previous
// h-slices at LLC scope (sc1) and demotes itself permanently to LLC ops.
// Stuck blocks heal themselves; ahead blocks stall within 1 step (skew
// bound) and heal too -> guaranteed progress; worst case == R8 exactly.
__global__ __launch_bounds__(256, 1) void lstm_persist(
    const float* __restrict__ x,
    const float* __restrict__ w_ih,
    const float* __restrict__ w_hh,
    const float* __restrict__ b_ih,
    const float* __restrict__ b_hh,
    const float* __restrict__ w_fc,
    const float* __restrict__ b_fc,
    float* __restrict__ out,          // [1024][48] fp32, plain stores
    _Float16* __restrict__ hbuf)      // [2][1024][512] fp16 ping-pong, tagged
{
  const int bid  = blockIdx.x;
  const int grp  = bid & (NGRP - 1);  // 8 blocks, same XCD under round-robin
  const int ub   = bid >> 5;
  const int tid  = threadIdx.x;
  const int wid  = tid >> 6;
  const int lane = tid & 63;
  const int quad = lane >> 4;
  const int lcol = lane & 15;
  const int b0   = grp * GBAT;
  const int myu  = ub * UBU + wid * 16 + lcol;
  const int uoff = ub * UBU + wid * 16 + (lcol & ~3);  // own 8B-pack unit base

  __shared__ __align__(16) _Float16 hs[GBAT][520];   // staged h_t (33.3 KB)
  __shared__ __align__(16) _Float16 wz[520];         // fp16 w_fc + zero pad

  for (int k = tid; k < 512; k += 256) wz[k] = (_Float16)w_fc[k];
  if (tid < 8) wz[512 + tid] = (_Float16)0.f;

  // ---- full-K weight B-frags (n=lcol, k=kc*32+quad*8+j) ----
  f16x8 wf[4][16];
  float wih[4], bias[4];
#pragma unroll
  for (int nt = 0; nt < 4; ++nt) {
    const int j = nt * HDIM + myu;
    wih[nt]  = w_ih[j];
    bias[nt] = b_ih[j] + b_hh[j];
#pragma unroll
    for (int kc = 0; kc < 16; ++kc) {
      const float* s = w_hh + (size_t)j * HDIM + kc * 32 + quad * 8;
      f16x8 v;
#pragma unroll
      for (int i = 0; i < 8; ++i) v[i] = (_Float16)s[i];
      wf[nt][kc] = v;
    }
  }
  const float bfc = b_fc[0];

  float cst[2][4];
#pragma unroll
  for (int mt = 0; mt < 2; ++mt)
#pragma unroll
    for (int r = 0; r < 4; ++r) cst[mt][r] = 0.f;

  u64 ownpack[2]  = {0ull, 0ull};    // own h_t packs (h_0 = 0, tag 00)
  u64 prevpack[2] = {0ull, 0ull};    // own h_{t-1} packs (self-heal history)
  int lmode = 0;                     // 0 = L2-scope exchange, 1 = LLC (sticky)

  const int srow = tid >> 3;          // staging row 0..31
  const int sc16 = tid & 7;           // 16B chunk in a 64-unit slice

  for (int t = 0; t <= STEPS; ++t) {
    const _Float16* hcur = hbuf + (size_t)(t & 1) * BATCH * HDIM;
    _Float16*       hnxt = hbuf + (size_t)((t + 1) & 1) * BATCH * HDIM;
    const u64 expect = tag_of(t);
    const bool dec = (t >= TENC);

    __syncthreads();   // all waves done reading hs (prev GEMM)

    // ---- own slice -> LDS directly (never round-trips) ----
#pragma unroll
    for (int mt = 0; mt < 2; ++mt)
      *reinterpret_cast<u64*>(
          &hs[mt * 16 + quad * 4 + (lcol & 3)][uoff]) = ownpack[mt];

    // ---- encoder x_t (plain cached loads; overlap staging RT) ----
    float xtv[2][4];
    if (!dec) {
#pragma unroll
      for (int mt = 0; mt < 2; ++mt)
#pragma unroll
        for (int r = 0; r < 4; ++r)
          xtv[mt][r] = x[(size_t)(b0 + mt * 16 + quad * 4 + r) * TENC + t];
    }

    // ---- 7 remote slices: all loads in flight, tag-validate, self-heal ----
    const _Float16* rbase = hcur + (size_t)(b0 + srow) * HDIM + sc16 * 8;
    f16x8 tmp[7];
#pragma unroll
    for (int i = 0; i < 7; ++i) {
      const int p = i + (i >= ub);
      tmp[i] = lmode ? load16_llc(rbase + p * UBU) : load16_l2(rbase + p * UBU);
    }
    asm volatile("s_waitcnt vmcnt(0)" ::: "memory");
    {
      unsigned stale = 0x7f;
      int tries = 0;
      for (;;) {
        unsigned ns = 0;
#pragma unroll
        for (int i = 0; i < 7; ++i)
          if (stale & (1u << i)) {
            u64x2 w2 = __builtin_bit_cast(u64x2, tmp[i]);
            if (((w2[0] & TAG_MASK) != expect) || ((w2[1] & TAG_MASK) != expect))
              ns |= 1u << i;
          }
        if (ns == 0) break;
        if ((++tries & (LIMIT - 1)) == 0) {
          // self-heal: republish own h_t AND h_{t-1} packs at LLC scope.
          // (prev lives in buffer (t-1)&1 == (t+1)&1 == hnxt; overwritten
          // later this step only after the whole group passed step t-1.)
#pragma unroll
          for (int mt = 0; mt < 2; ++mt) {
            const int rb = b0 + mt * 16 + quad * 4 + (lcol & 3);
            __hip_atomic_store((u64*)((_Float16*)hcur + (size_t)rb * HDIM + uoff),
                               ownpack[mt], __ATOMIC_RELAXED, __HIP_MEMORY_SCOPE_AGENT);
            __hip_atomic_store((u64*)(hnxt + (size_t)rb * HDIM + uoff),
                               prevpack[mt], __ATOMIC_RELAXED, __HIP_MEMORY_SCOPE_AGENT);
          }
          lmode = 1;   // permanent demotion to LLC scope
        }
        __builtin_amdgcn_s_sleep(1);
#pragma unroll
        for (int i = 0; i < 7; ++i)
          if (ns & (1u << i)) {
            const int p = i + (i >= ub);
            tmp[i] = lmode ? load16_llc(rbase + p * UBU)
                           : load16_l2(rbase + p * UBU);
          }
        asm volatile("s_waitcnt vmcnt(0)" ::: "memory");
        stale = ns;
      }
    }
#pragma unroll
    for (int i = 0; i < 7; ++i) {
      const int p = i + (i >= ub);
      *reinterpret_cast<f16x8*>(&hs[srow][p * UBU + sc16 * 8]) = tmp[i];
    }
    __syncthreads();   // full h_t staged

    // ---- GEMM (+fc row in decode) from LDS ----
    f32x4 acc[2][4];
#pragma unroll
    for (int mt = 0; mt < 2; ++mt)
#pragma unroll
      for (int nt = 0; nt < 4; ++nt) acc[mt][nt] = (f32x4){0.f, 0.f, 0.f, 0.f};
    f32x4 accF[2];
    accF[0] = (f32x4){0.f, 0.f, 0.f, 0.f};
    accF[1] = (f32x4){0.f, 0.f, 0.f, 0.f};

#pragma unroll
    for (int kc = 0; kc < 16; ++kc) {
      const f16x8 a0 = *reinterpret_cast<const f16x8*>(&hs[lcol][kc * 32 + quad * 8]);
      const f16x8 a1 = *reinterpret_cast<const f16x8*>(&hs[16 + lcol][kc * 32 + quad * 8]);
#pragma unroll
      for (int nt = 0; nt < 4; ++nt) {
        acc[0][nt] = __builtin_amdgcn_mfma_f32_16x16x32_f16(a0, wf[nt][kc], acc[0][nt], 0, 0, 0);
        acc[1][nt] = __builtin_amdgcn_mfma_f32_16x16x32_f16(a1, wf[nt][kc], acc[1][nt], 0, 0, 0);
      }
      if (dec) {   // fc: B row 0 = w_fc, rows 1..15 = 0 (zero-pad broadcast)
        const f16x8 wv = *reinterpret_cast<const f16x8*>(
            &wz[(lcol == 0) ? (kc * 32 + quad * 8) : 512]);
        accF[0] = __builtin_amdgcn_mfma_f32_16x16x32_f16(a0, wv, accF[0], 0, 0, 0);
        accF[1] = __builtin_amdgcn_mfma_f32_16x16x32_f16(a1, wv, accF[1], 0, 0, 0);
      }
    }

    // ---- decode: xt = fc(h_t) (redundant per block, zero communication) ----
    if (dec) {
#pragma unroll
      for (int mt = 0; mt < 2; ++mt)
#pragma unroll
        for (int r = 0; r < 4; ++r)
          xtv[mt][r] = __shfl(accF[mt][r], quad * 16) + bfc;
      if (ub == 0 && wid == 0 && lcol == 0) {
        const int p = t - TENC;
#pragma unroll
        for (int mt = 0; mt < 2; ++mt)
#pragma unroll
          for (int r = 0; r < 4; ++r)
            out[(size_t)(b0 + mt * 16 + quad * 4 + r) * PRED + p] =
                accF[mt][r] + bfc;
      }
    }

    // ---- cell update + tagged publish (tags carry the sync, no drains) ----
    if (t < STEPS) {
      const u64 tagnew = tag_of(t + 1);
#pragma unroll
      for (int mt = 0; mt < 2; ++mt) {
#pragma unroll
        for (int r = 0; r < 4; ++r) {
          const int b = b0 + mt * 16 + quad * 4 + r;
          const float xt = xtv[mt][r];
          const float gi = acc[mt][0][r] + xt * wih[0] + bias[0];
          const float gf = acc[mt][1][r] + xt * wih[1] + bias[1];
          const float gg = acc[mt][2][r] + xt * wih[2] + bias[2];
          const float go = acc[mt][3][r] + xt * wih[3] + bias[3];
          const float si = 1.f / (1.f + __expf(-gi));
          const float sf = 1.f / (1.f + __expf(-gf));
          const float so = 1.f / (1.f + __expf(-go));
          const float tg = 1.f - 2.f / (1.f + __expf(2.f * gg));
          const float cn = sf * cst[mt][r] + si * tg;
          cst[mt][r] = cn;
          const float tc = 1.f - 2.f / (1.f + __expf(2.f * cn));
          const float hn = so * tc;

          // pack 4 adjacent units across lanes -> 8B tagged pack
          const unsigned short hb = __builtin_bit_cast(unsigned short, (_Float16)hn);
          const unsigned v0  = hb;
          const unsigned o0  = (unsigned)__shfl_xor((int)v0, 1);
          const unsigned p01 = (lcol & 1) ? ((v0 << 16) | o0) : ((o0 << 16) | v0);
          const unsigned q   = (unsigned)__shfl_xor((int)p01, 2);
          u64 p4 = (lcol & 2) ? (((u64)p01 << 32) | (u64)q)
                              : (((u64)q << 32) | (u64)p01);
          p4 = (p4 & ~TAG_MASK) | tagnew;
          if ((lcol & 3) == r) {            // owner lane for (mt, r)
            prevpack[mt] = ownpack[mt];     // keep 1-step history for self-heal
            ownpack[mt]  = p4;
            _Float16* dst = hnxt + (size_t)b * HDIM + uoff;
            if (lmode)
              __hip_atomic_store((u64*)dst, p4, __ATOMIC_RELAXED,
                                 __HIP_MEMORY_SCOPE_AGENT);
            else
              store8_l2(dst, p4);
          }
        }
      }
    }
  }
}

extern "C" void kernel_launch(void* const* d_in, const int* in_sizes, int n_in,
                              void* d_out, int out_size, void* d_ws, size_t ws_size,
                              hipStream_t stream) {
  const float* x    = (const float*)d_in[0];
  const float* w_ih = (const float*)d_in[1];
  const float* w_hh = (const float*)d_in[2];
  const float* b_ih = (const float*)d_in[3];
  const float* b_hh = (const float*)d_in[4];
  const float* w_fc = (const float*)d_in[5];
  const float* b_fc = (const float*)d_in[6];
  float* out = (float*)d_out;
  _Float16* hbuf = (_Float16*)((char*)d_ws + HB_OFF);

  hipLaunchKernelGGL(init_kernel, dim3(256), dim3(256), 0, stream, (int*)d_ws);
  hipLaunchKernelGGL(lstm_persist, dim3(NGRP * 8), dim3(256), 0, stream,
                     x, w_ih, w_hh, b_ih, b_hh, w_fc, b_fc, out, hbuf);
}

// Round 11
// 3496.581 us; speedup vs baseline: 8.5589x; 8.5589x over previous
//
#include <hip/hip_runtime.h>

typedef _Float16 f16x8 __attribute__((ext_vector_type(8)));
typedef float    f32x4 __attribute__((ext_vector_type(4)));
typedef unsigned long long u64;
typedef u64 u64x2 __attribute__((ext_vector_type(2)));

constexpr int BATCH = 1024;
constexpr int HDIM  = 512;
constexpr int TENC  = 512;
constexpr int PRED  = 48;
constexpr int STEPS = TENC + PRED - 1;   // 559 cell steps; loop runs 560 (last = fc only)
constexpr int NG    = 64;                // groups (16 batches each)
constexpr int GB    = 16;                // batches per group = one MFMA m-tile
constexpr int UBU   = 64;                // units per block (4 waves x 16)
constexpr int HB_OFF = 32768;

// In-band tag (R7/R8-proven): each 4B dword of stored h carries step tag at
// bit0/bit16. h_t in buffer t&1, tag t&3; skew <= 1 step (data dependency)
// => 2-bit tag + ping-pong is ABA-safe. LLC scope only (R10: per-XCD L2 is
// NOT a usable exchange medium on gfx950).
constexpr u64 TAG_MASK = 0x0001000100010001ull;
__device__ __forceinline__ u64 tag_of(int t) {
  return ((u64)(t & 1) | ((u64)((t >> 1) & 1) << 16)) * 0x0000000100000001ull;
}

__global__ void init_kernel(int* wsi) {
  int idx = blockIdx.x * blockDim.x + threadIdx.x;
  int stride = gridDim.x * blockDim.x;
  const int nws = (HB_OFF + BATCH * HDIM * 2) / 4;  // hbuf[0] = h_0 = 0 (tag 00)
  for (int i = idx; i < nws; i += stride) wsi[i] = 0;
  // hbuf[1] stays 0xAA poison -> tag-invalid until written
}

static __device__ __forceinline__ f16x8 load16_llc(const _Float16* p) {
  f16x8 v;
  asm volatile("global_load_dwordx4 %0, %1, off sc0 sc1"
               : "=v"(v) : "v"((u64)p) : "memory");
  return v;
}
static __device__ __forceinline__ float loadx(const float* p) {
  float v;   // plain cached load via asm so compiler never vmcnt(0)-drains our prefetch
  asm volatile("global_load_dword %0, %1, off"
               : "=v"(v) : "v"((u64)p) : "memory");
  return v;
}

// Two interleaved 16-batch recurrences per block (A: grp=bid>>3, B: grp+32),
// same 64-unit weight tile for both. Phase pipeline: B's remote loads fly
// during A's GEMM+epilogue and vice versa -> the LLC visibility round trip
// is hidden behind the other group's compute. Protocol = R8 verbatim.
__global__ __launch_bounds__(256, 1) void lstm_persist(
    const float* __restrict__ x,
    const float* __restrict__ w_ih,
    const float* __restrict__ w_hh,
    const float* __restrict__ b_ih,
    const float* __restrict__ b_hh,
    const float* __restrict__ w_fc,
    const float* __restrict__ b_fc,
    float* __restrict__ out,          // [1024][48] fp32, plain stores
    _Float16* __restrict__ hbuf)      // [2][1024][512] fp16 ping-pong, tagged
{
  const int bid  = blockIdx.x;
  const int gA   = bid >> 3;          // group A (0..31); B = gA+32
  const int ub   = bid & 7;
  const int tid  = threadIdx.x;
  const int wid  = tid >> 6;
  const int lane = tid & 63;
  const int quad = lane >> 4;
  const int lcol = lane & 15;
  const int bA0  = gA * GB;
  const int bB0  = bA0 + NG / 2 * GB; // = bA0 + 512
  const int myu  = ub * UBU + wid * 16 + lcol;
  const int uoff = ub * UBU + wid * 16 + (lcol & ~3);

  __shared__ __align__(16) _Float16 hsA[GB][520];    // 16.6 KB
  __shared__ __align__(16) _Float16 hsB[GB][520];    // 16.6 KB
  __shared__ __align__(16) _Float16 wz[520];         // fp16 w_fc + zero pad

  for (int k = tid; k < 512; k += 256) wz[k] = (_Float16)w_fc[k];
  if (tid < 8) wz[512 + tid] = (_Float16)0.f;

  // ---- full-K weight B-frags (n=lcol, k=kc*32+quad*8+j) ----
  f16x8 wf[4][16];
  float wih[4], bias[4];
#pragma unroll
  for (int nt = 0; nt < 4; ++nt) {
    const int j = nt * HDIM + myu;
    wih[nt]  = w_ih[j];
    bias[nt] = b_ih[j] + b_hh[j];
#pragma unroll
    for (int kc = 0; kc < 16; ++kc) {
      const float* s = w_hh + (size_t)j * HDIM + kc * 32 + quad * 8;
      f16x8 v;
#pragma unroll
      for (int i = 0; i < 8; ++i) v[i] = (_Float16)s[i];
      wf[nt][kc] = v;
    }
  }
  const float bfc = b_fc[0];

  float cstA[4], cstB[4];
#pragma unroll
  for (int r = 0; r < 4; ++r) { cstA[r] = 0.f; cstB[r] = 0.f; }

  // staging: 16 rows x 512 units = 1024 16B-chunks; thread covers 4
  // (c = i*256+tid: row=c>>6, col16=c&63). Includes own slice (own
  // store->load via LLC is same-thread ordered; R7-verified).
  f16x8 tA[4], tB[4];

  auto issue4 = [&](f16x8* tr, const _Float16* base) {
#pragma unroll
    for (int i = 0; i < 4; ++i) {
      const int c = i * 256 + tid;
      tr[i] = load16_llc(base + (size_t)(c >> 6) * HDIM + (c & 63) * 8);
    }
  };
  auto validate4 = [&](f16x8* tr, const _Float16* base, u64 expect) {
    unsigned stale = 0xf;
    for (;;) {
      unsigned ns = 0;
#pragma unroll
      for (int i = 0; i < 4; ++i)
        if (stale & (1u << i)) {
          u64x2 w2 = __builtin_bit_cast(u64x2, tr[i]);
          if (((w2[0] & TAG_MASK) != expect) || ((w2[1] & TAG_MASK) != expect))
            ns |= 1u << i;
        }
      if (ns == 0) break;
      __builtin_amdgcn_s_sleep(1);
#pragma unroll
      for (int i = 0; i < 4; ++i)
        if (ns & (1u << i)) {
          const int c = i * 256 + tid;
          tr[i] = load16_llc(base + (size_t)(c >> 6) * HDIM + (c & 63) * 8);
        }
      asm volatile("s_waitcnt vmcnt(0)" ::: "memory");
      stale = ns;
    }
  };
  auto stage4 = [&](f16x8* tr, _Float16 (*hsp)[520]) {
#pragma unroll
    for (int i = 0; i < 4; ++i) {
      const int c = i * 256 + tid;
      *reinterpret_cast<f16x8*>(&hsp[c >> 6][(c & 63) * 8]) = tr[i];
    }
  };
  auto gemm = [&](const _Float16 (*hsp)[520], f32x4* acc, f32x4& accF, bool dec) {
#pragma unroll
    for (int kc = 0; kc < 16; ++kc) {
      const f16x8 a = *reinterpret_cast<const f16x8*>(&hsp[lcol][kc * 32 + quad * 8]);
#pragma unroll
      for (int nt = 0; nt < 4; ++nt)
        acc[nt] = __builtin_amdgcn_mfma_f32_16x16x32_f16(a, wf[nt][kc], acc[nt], 0, 0, 0);
      if (dec) {   // fc: B row 0 = w_fc, rows 1..15 = 0 (zero-pad broadcast)
        const f16x8 wv = *reinterpret_cast<const f16x8*>(
            &wz[(lcol == 0) ? (kc * 32 + quad * 8) : 512]);
        accF = __builtin_amdgcn_mfma_f32_16x16x32_f16(a, wv, accF, 0, 0, 0);
      }
    }
  };
  auto tail = [&](f32x4* acc, f32x4& accF, float* xv, float* cstv,
                  int bX0, int t, _Float16* hnxt, bool dec) {
    if (dec) {   // xt = fc(h_t), redundant per block; preds stored by ub0/w0
#pragma unroll
      for (int r = 0; r < 4; ++r) xv[r] = __shfl(accF[r], quad * 16) + bfc;
      if (ub == 0 && wid == 0 && lcol == 0) {
        const int p = t - TENC;
#pragma unroll
        for (int r = 0; r < 4; ++r)
          out[(size_t)(bX0 + quad * 4 + r) * PRED + p] = accF[r] + bfc;
      }
    }
    if (t < STEPS) {
      const u64 tagnew = tag_of(t + 1);
#pragma unroll
      for (int r = 0; r < 4; ++r) {
        const float xt = xv[r];
        const float gi = acc[0][r] + xt * wih[0] + bias[0];
        const float gf = acc[1][r] + xt * wih[1] + bias[1];
        const float gg = acc[2][r] + xt * wih[2] + bias[2];
        const float go = acc[3][r] + xt * wih[3] + bias[3];
        const float si = 1.f / (1.f + __expf(-gi));
        const float sf = 1.f / (1.f + __expf(-gf));
        const float so = 1.f / (1.f + __expf(-go));
        const float tg = 1.f - 2.f / (1.f + __expf(2.f * gg));
        const float cn = sf * cstv[r] + si * tg;
        cstv[r] = cn;
        const float tc = 1.f - 2.f / (1.f + __expf(2.f * cn));
        const float hn = so * tc;

        const unsigned short hb = __builtin_bit_cast(unsigned short, (_Float16)hn);
        const unsigned v0  = hb;
        const unsigned o0  = (unsigned)__shfl_xor((int)v0, 1);
        const unsigned p01 = (lcol & 1) ? ((v0 << 16) | o0) : ((o0 << 16) | v0);
        const unsigned q   = (unsigned)__shfl_xor((int)p01, 2);
        u64 p4 = (lcol & 2) ? (((u64)p01 << 32) | (u64)q)
                            : (((u64)q << 32) | (u64)p01);
        p4 = (p4 & ~TAG_MASK) | tagnew;
        if ((lcol & 3) == r) {
          _Float16* dst = hnxt + (size_t)(bX0 + quad * 4 + r) * HDIM + uoff;
          __hip_atomic_store((u64*)dst, p4, __ATOMIC_RELAXED,
                             __HIP_MEMORY_SCOPE_AGENT);
        }
      }
    }
  };

  issue4(tA, hbuf + (size_t)bA0 * HDIM);   // prologue: A(0) in flight

  for (int t = 0; t <= STEPS; ++t) {
    const _Float16* hcur = hbuf + (size_t)(t & 1) * BATCH * HDIM;
    _Float16*       hnxt = hbuf + (size_t)((t + 1) & 1) * BATCH * HDIM;
    const u64 expect = tag_of(t);
    const bool dec = (t >= TENC);

    // ================= phase A =================
    float xA[4];
    if (!dec) {
#pragma unroll
      for (int r = 0; r < 4; ++r)
        xA[r] = loadx(x + (size_t)(bA0 + quad * 4 + r) * TENC + t);
    }
    asm volatile("s_waitcnt vmcnt(0)" ::: "memory");   // tA (+xA) landed
    validate4(tA, hcur + (size_t)bA0 * HDIM, expect);
    stage4(tA, hsA);
    __syncthreads();
    issue4(tB, hcur + (size_t)bB0 * HDIM);             // B(t) flies during A compute

    f32x4 accA[4], accFA;
#pragma unroll
    for (int nt = 0; nt < 4; ++nt) accA[nt] = (f32x4){0.f, 0.f, 0.f, 0.f};
    accFA = (f32x4){0.f, 0.f, 0.f, 0.f};
    gemm(hsA, accA, accFA, dec);
    tail(accA, accFA, xA, cstA, bA0, t, hnxt, dec);

    // ================= phase B =================
    float xB[4];
    if (!dec) {
#pragma unroll
      for (int r = 0; r < 4; ++r)
        xB[r] = loadx(x + (size_t)(bB0 + quad * 4 + r) * TENC + t);
    }
    asm volatile("s_waitcnt vmcnt(0)" ::: "memory");   // tB (+xB, A-publish) landed
    validate4(tB, hcur + (size_t)bB0 * HDIM, expect);
    stage4(tB, hsB);
    __syncthreads();
    if (t < STEPS)
      issue4(tA, hnxt + (size_t)bA0 * HDIM);           // A(t+1) flies during B compute

    f32x4 accB[4], accFB;
#pragma unroll
    for (int nt = 0; nt < 4; ++nt) accB[nt] = (f32x4){0.f, 0.f, 0.f, 0.f};
    accFB = (f32x4){0.f, 0.f, 0.f, 0.f};
    gemm(hsB, accB, accFB, dec);
    tail(accB, accFB, xB, cstB, bB0, t, hnxt, dec);
  }
}

extern "C" void kernel_launch(void* const* d_in, const int* in_sizes, int n_in,
                              void* d_out, int out_size, void* d_ws, size_t ws_size,
                              hipStream_t stream) {
  const float* x    = (const float*)d_in[0];
  const float* w_ih = (const float*)d_in[1];
  const float* w_hh = (const float*)d_in[2];
  const float* b_ih = (const float*)d_in[3];
  const float* b_hh = (const float*)d_in[4];
  const float* w_fc = (const float*)d_in[5];
  const float* b_fc = (const float*)d_in[6];
  float* out = (float*)d_out;
  _Float16* hbuf = (_Float16*)((char*)d_ws + HB_OFF);

  hipLaunchKernelGGL(init_kernel, dim3(256), dim3(256), 0, stream, (int*)d_ws);
  hipLaunchKernelGGL(lstm_persist, dim3(256), dim3(256), 0, stream,
                     x, w_ih, w_hh, b_ih, b_hh, w_fc, b_fc, out, hbuf);
}